// Round 1
// baseline (235.001 us; speedup 1.0000x reference)
//
#include <hip/hip_runtime.h>
#include <cstdint>
#include <cstddef>

#define TOKENS 8192
#define IN_F   4096
#define OUT_F  4096
#define QMAXF  127.0f
#define EPSF   1e-8f

typedef int   int32x4 __attribute__((ext_vector_type(4)));

__device__ __forceinline__ void gload16(const void* g, void* l) {
    __builtin_amdgcn_global_load_lds(
        (const __attribute__((address_space(1))) void*)g,
        (__attribute__((address_space(3))) void*)l,
        16, 0, 0);
}

__device__ __forceinline__ int quant1(float v, float inv) {
    int q = (int)rintf(v * inv);
    q = q > 127 ? 127 : q;
    q = q < -127 ? -127 : q;
    return q;
}

__device__ __forceinline__ unsigned int pack4i(int a, int b, int c, int d) {
    return (unsigned int)(a & 255) | ((unsigned int)(b & 255) << 8) |
           ((unsigned int)(c & 255) << 16) | ((unsigned int)(d & 255) << 24);
}

// One block per token: absmax reduce + int8 quantize.
__global__ __launch_bounds__(256) void quant_x_kernel(const float* __restrict__ x,
                                                      signed char* __restrict__ xq,
                                                      float* __restrict__ xscale) {
    const int t   = blockIdx.x;
    const int tid = threadIdx.x;
    const float* xr = x + (size_t)t * IN_F + tid * 16;

    float4 v[4];
    float am = 0.0f;
#pragma unroll
    for (int i = 0; i < 4; ++i) {
        v[i] = ((const float4*)xr)[i];
        am = fmaxf(am, fmaxf(fmaxf(fabsf(v[i].x), fabsf(v[i].y)),
                             fmaxf(fabsf(v[i].z), fabsf(v[i].w))));
    }
#pragma unroll
    for (int off = 32; off >= 1; off >>= 1)
        am = fmaxf(am, __shfl_xor(am, off));

    __shared__ float wmax[4];
    const int wid = tid >> 6, lane = tid & 63;
    if (lane == 0) wmax[wid] = am;
    __syncthreads();
    am = fmaxf(fmaxf(wmax[0], wmax[1]), fmaxf(wmax[2], wmax[3]));

    const float s   = fmaxf(am, EPSF) / QMAXF;
    const float inv = QMAXF / fmaxf(am, EPSF);
    if (tid == 0) xscale[t] = s;

    unsigned int w[4];
#pragma unroll
    for (int i = 0; i < 4; ++i) {
        w[i] = pack4i(quant1(v[i].x, inv), quant1(v[i].y, inv),
                      quant1(v[i].z, inv), quant1(v[i].w, inv));
    }
    *(uint4*)(xq + (size_t)t * IN_F + tid * 16) = make_uint4(w[0], w[1], w[2], w[3]);
}

// Repack int32-held int8 weights into dense int8.
__global__ __launch_bounds__(256) void pack_w_kernel(const int* __restrict__ w,
                                                     signed char* __restrict__ wq) {
    const size_t idx = (size_t)blockIdx.x * 256 + threadIdx.x;  // 1048576 threads, 16 elems each
    const int4* src = (const int4*)w + idx * 4;
    unsigned int o[4];
#pragma unroll
    for (int i = 0; i < 4; ++i) {
        int4 u = src[i];
        o[i] = pack4i(u.x, u.y, u.z, u.w);
    }
    ((uint4*)wq)[idx] = make_uint4(o[0], o[1], o[2], o[3]);
}

// 128x128 tile int8 GEMM, BK=64, 4 waves (2x2), 4x4 16x16x64 fragments per wave.
// A = xq [TOKENS][IN_F], B^T = wq [OUT_F][IN_F]; fused dequant epilogue.
__global__ __launch_bounds__(256) void gemm_kernel(const signed char* __restrict__ xq,
                                                   const signed char* __restrict__ wq,
                                                   const float* __restrict__ xscale,
                                                   const float* __restrict__ wscale,
                                                   const float* __restrict__ bias,
                                                   float* __restrict__ out) {
    __shared__ __align__(16) signed char As[128 * 64];
    __shared__ __align__(16) signed char Bs[128 * 64];

    const int tid  = threadIdx.x;
    const int wid  = tid >> 6;
    const int lane = tid & 63;
    const int bid  = blockIdx.x;
    const int bn0  = (bid & 31) * 128;   // 32 n-tiles
    const int bm0  = (bid >> 5) * 128;   // 64 m-tiles

    // staging addressing: thread t, round r covers tile bytes [(r*256+t)*16, +16)
    const int rt = tid >> 2;             // row within 64-row half
    const int ct = (tid & 3) * 16;       // col byte
    const signed char* pa0 = xq + (size_t)(bm0 + rt) * IN_F + ct;
    const signed char* pa1 = xq + (size_t)(bm0 + 64 + rt) * IN_F + ct;
    const signed char* pb0 = wq + (size_t)(bn0 + rt) * IN_F + ct;
    const signed char* pb1 = wq + (size_t)(bn0 + 64 + rt) * IN_F + ct;
    signed char* lA0 = As + wid * 1024;
    signed char* lA1 = As + 4096 + wid * 1024;
    signed char* lB0 = Bs + wid * 1024;
    signed char* lB1 = Bs + 4096 + wid * 1024;

    const int wr = wid >> 1, wc = wid & 1;       // 2x2 wave grid, 64x64 each
    const int rA = wr * 64 + (lane & 15);
    const int rB = wc * 64 + (lane & 15);
    const int kb = (lane >> 4) * 16;

    int32x4 acc[4][4] = {};

    for (int kt = 0; kt < IN_F; kt += 64) {
        gload16(pa0 + kt, lA0);
        gload16(pa1 + kt, lA1);
        gload16(pb0 + kt, lB0);
        gload16(pb1 + kt, lB1);
        __syncthreads();

        int32x4 a[4], b[4];
#pragma unroll
        for (int m = 0; m < 4; ++m)
            a[m] = *(const int32x4*)&As[(rA + m * 16) * 64 + kb];
#pragma unroll
        for (int n = 0; n < 4; ++n)
            b[n] = *(const int32x4*)&Bs[(rB + n * 16) * 64 + kb];
#pragma unroll
        for (int m = 0; m < 4; ++m)
#pragma unroll
            for (int n = 0; n < 4; ++n)
                acc[m][n] = __builtin_amdgcn_mfma_i32_16x16x64_i8(a[m], b[n], acc[m][n], 0, 0, 0);
        __syncthreads();
    }

    // epilogue: C/D layout col=lane&15, row=(lane>>4)*4+reg
    const int r0 = bm0 + wr * 64 + (lane >> 4) * 4;
    const int c0 = bn0 + wc * 64 + (lane & 15);
#pragma unroll
    for (int n = 0; n < 4; ++n) {
        const int col = c0 + n * 16;
        const float wsc = wscale[col];
        const float bv  = bias[col];
#pragma unroll
        for (int m = 0; m < 4; ++m) {
#pragma unroll
            for (int j = 0; j < 4; ++j) {
                const int row = r0 + m * 16 + j;
                out[(size_t)row * OUT_F + col] =
                    (float)acc[m][n][j] * xscale[row] * wsc + bv;
            }
        }
    }
}

extern "C" void kernel_launch(void* const* d_in, const int* in_sizes, int n_in,
                              void* d_out, int out_size, void* d_ws, size_t ws_size,
                              hipStream_t stream) {
    const float* x      = (const float*)d_in[0];
    const int*   w      = (const int*)d_in[1];     // int8 weights held as int32
    const float* wscale = (const float*)d_in[2];
    const float* bias   = (const float*)d_in[3];
    float* out = (float*)d_out;

    char* ws = (char*)d_ws;
    signed char* xq  = (signed char*)ws;                                   // 33.5 MB
    signed char* wq8 = (signed char*)(ws + (size_t)TOKENS * IN_F);         // 16.8 MB
    float* xscale    = (float*)(ws + (size_t)TOKENS * IN_F + (size_t)OUT_F * IN_F);

    quant_x_kernel<<<TOKENS, 256, 0, stream>>>(x, xq, xscale);
    pack_w_kernel<<<(OUT_F * (IN_F / 16)) / 256, 256, 0, stream>>>(w, wq8);
    gemm_kernel<<<(TOKENS / 128) * (OUT_F / 128), 256, 0, stream>>>(
        xq, wq8, xscale, wscale, bias, out);
}

// Round 2
// 211.276 us; speedup vs baseline: 1.1123x; 1.1123x over previous
//
#include <hip/hip_runtime.h>
#include <cstdint>
#include <cstddef>

#define TOKENS 8192
#define IN_F   4096
#define OUT_F  4096
#define QMAXF  127.0f
#define EPSF   1e-8f

typedef int i32x4  __attribute__((ext_vector_type(4)));
typedef int i32x16 __attribute__((ext_vector_type(16)));

#define BKB 64                    // K-bytes (= int8 elems) per K-tile
#define NT  (IN_F / BKB)          // 64 K-tiles
#define LDS_BUF   32768           // A 16KB + B 16KB per buffer
#define LDS_TOTAL (3 * LDS_BUF)   // 98304 bytes

__device__ __forceinline__ void gload16(const void* g, void* l) {
    __builtin_amdgcn_global_load_lds(
        (const __attribute__((address_space(1))) void*)g,
        (__attribute__((address_space(3))) void*)l,
        16, 0, 0);
}

__device__ __forceinline__ void bar() {
    asm volatile("" ::: "memory");
    __builtin_amdgcn_s_barrier();
    asm volatile("" ::: "memory");
}

__device__ __forceinline__ int quant1(float v, float inv) {
    int q = (int)rintf(v * inv);
    q = q > 127 ? 127 : q;
    q = q < -127 ? -127 : q;
    return q;
}

__device__ __forceinline__ unsigned int pack4i(int a, int b, int c, int d) {
    return (unsigned int)(a & 255) | ((unsigned int)(b & 255) << 8) |
           ((unsigned int)(c & 255) << 16) | ((unsigned int)(d & 255) << 24);
}

// One block per token: absmax reduce + int8 quantize.
__global__ __launch_bounds__(256) void quant_x_kernel(const float* __restrict__ x,
                                                      signed char* __restrict__ xq,
                                                      float* __restrict__ xscale) {
    const int t   = blockIdx.x;
    const int tid = threadIdx.x;
    const float* xr = x + (size_t)t * IN_F + tid * 16;

    float4 v[4];
    float am = 0.0f;
#pragma unroll
    for (int i = 0; i < 4; ++i) {
        v[i] = ((const float4*)xr)[i];
        am = fmaxf(am, fmaxf(fmaxf(fabsf(v[i].x), fabsf(v[i].y)),
                             fmaxf(fabsf(v[i].z), fabsf(v[i].w))));
    }
#pragma unroll
    for (int off = 32; off >= 1; off >>= 1)
        am = fmaxf(am, __shfl_xor(am, off));

    __shared__ float wmax[4];
    const int wid = tid >> 6, lane = tid & 63;
    if (lane == 0) wmax[wid] = am;
    __syncthreads();
    am = fmaxf(fmaxf(wmax[0], wmax[1]), fmaxf(wmax[2], wmax[3]));

    const float s   = fmaxf(am, EPSF) / QMAXF;
    const float inv = QMAXF / fmaxf(am, EPSF);
    if (tid == 0) xscale[t] = s;

    unsigned int w[4];
#pragma unroll
    for (int i = 0; i < 4; ++i) {
        w[i] = pack4i(quant1(v[i].x, inv), quant1(v[i].y, inv),
                      quant1(v[i].z, inv), quant1(v[i].w, inv));
    }
    *(uint4*)(xq + (size_t)t * IN_F + tid * 16) = make_uint4(w[0], w[1], w[2], w[3]);
}

// Repack int32-held int8 weights into dense int8.
__global__ __launch_bounds__(256) void pack_w_kernel(const int* __restrict__ w,
                                                     signed char* __restrict__ wq) {
    const size_t idx = (size_t)blockIdx.x * 256 + threadIdx.x;
    const int4* src = (const int4*)w + idx * 4;
    unsigned int o[4];
#pragma unroll
    for (int i = 0; i < 4; ++i) {
        int4 u = src[i];
        o[i] = pack4i(u.x, u.y, u.z, u.w);
    }
    ((uint4*)wq)[idx] = make_uint4(o[0], o[1], o[2], o[3]);
}

// 256x256 tile, BK=64B, 8 waves (2x4), mfma_i32_32x32x32_i8,
// 3-buffer LDS, stage-2-ahead, counted vmcnt(4), 2 phases/K-tile,
// XOR swizzle (granule ^= row&3) on stage-source + ds_read.
__global__ __launch_bounds__(512, 2) void gemm_kernel(const signed char* __restrict__ xq,
                                                      const signed char* __restrict__ wq,
                                                      const float* __restrict__ xscale,
                                                      const float* __restrict__ wscale,
                                                      const float* __restrict__ bias,
                                                      float* __restrict__ out) {
    extern __shared__ __align__(16) char lds[];

    const int tid  = threadIdx.x;
    const int wid  = tid >> 6;
    const int lane = tid & 63;
    const int wr   = wid >> 2;   // 0..1
    const int wc   = wid & 3;    // 0..3
    const int bid  = blockIdx.x;
    const int bm0  = (bid & 31) * 256;
    const int bn0  = (bid >> 5) * 256;

    // ---- staging (pre-swizzled global source, linear LDS dest) ----
    const int srow = tid >> 2;                       // 0..127 (row within round)
    const int sg   = tid & 3;                        // granule 0..3
    const int scol = ((sg ^ (srow & 3)) << 4);       // swizzled byte col in k-window
    const signed char* gA0 = xq + (size_t)(bm0 + srow)       * IN_F + scol;
    const signed char* gA1 = xq + (size_t)(bm0 + 128 + srow) * IN_F + scol;
    const signed char* gB0 = wq + (size_t)(bn0 + srow)       * IN_F + scol;
    const signed char* gB1 = wq + (size_t)(bn0 + 128 + srow) * IN_F + scol;
    const int ldst = tid * 16;

    // ---- fragment read offsets (swizzled) ----
    const int l31 = lane & 31, hi = lane >> 5, l3 = lane & 3;
    int a_off[4][2], b_off[2][2];
#pragma unroll
    for (int m = 0; m < 4; ++m) {
        const int row = wr * 128 + m * 32 + l31;
#pragma unroll
        for (int ks = 0; ks < 2; ++ks)
            a_off[m][ks] = row * 64 + (((ks * 2 + hi) ^ l3) << 4);
    }
#pragma unroll
    for (int n = 0; n < 2; ++n) {
        const int row = wc * 64 + n * 32 + l31;
#pragma unroll
        for (int ks = 0; ks < 2; ++ks)
            b_off[n][ks] = 16384 + row * 64 + (((ks * 2 + hi) ^ l3) << 4);
    }

    i32x16 acc[4][2];
#pragma unroll
    for (int m = 0; m < 4; ++m)
#pragma unroll
        for (int n = 0; n < 2; ++n)
#pragma unroll
            for (int r = 0; r < 16; ++r) acc[m][n][r] = 0;

    // ---- prologue: stage tile0 -> buf0, tile1 -> buf1 ----
    {
        char* S0 = lds;
        gload16(gA0,       S0 + ldst);
        gload16(gA1,       S0 + 8192  + ldst);
        gload16(gB0,       S0 + 16384 + ldst);
        gload16(gB1,       S0 + 24576 + ldst);
        char* S1 = lds + LDS_BUF;
        gload16(gA0 + BKB, S1 + ldst);
        gload16(gA1 + BKB, S1 + 8192  + ldst);
        gload16(gB0 + BKB, S1 + 16384 + ldst);
        gload16(gB1 + BKB, S1 + 24576 + ldst);
    }
    asm volatile("s_waitcnt vmcnt(4)" ::: "memory");
    bar();

    int cur = 0, nxt = 2;
    for (int t = 0; t < NT; ++t) {
        const char* Ab = lds + cur * LDS_BUF;
        char* Sd = lds + nxt * LDS_BUF;
        const bool st = (t + 2 < NT);
        const int koff = (t + 2) * BKB;

        // ---------- phase 0 (ks = 0) ----------
        i32x4 a0[4], b0[2];
#pragma unroll
        for (int m = 0; m < 4; ++m) a0[m] = *(const i32x4*)(Ab + a_off[m][0]);
#pragma unroll
        for (int n = 0; n < 2; ++n) b0[n] = *(const i32x4*)(Ab + b_off[n][0]);
        if (st) {
            gload16(gA0 + koff, Sd + ldst);
            gload16(gB0 + koff, Sd + 16384 + ldst);
        }
        bar();
        __builtin_amdgcn_s_setprio(1);
#pragma unroll
        for (int m = 0; m < 4; ++m)
#pragma unroll
            for (int n = 0; n < 2; ++n)
                acc[m][n] = __builtin_amdgcn_mfma_i32_32x32x32_i8(a0[m], b0[n], acc[m][n], 0, 0, 0);
        __builtin_amdgcn_s_setprio(0);
        bar();

        // ---------- phase 1 (ks = 1) ----------
        i32x4 a1[4], b1[2];
#pragma unroll
        for (int m = 0; m < 4; ++m) a1[m] = *(const i32x4*)(Ab + a_off[m][1]);
#pragma unroll
        for (int n = 0; n < 2; ++n) b1[n] = *(const i32x4*)(Ab + b_off[n][1]);
        if (st) {
            gload16(gA1 + koff, Sd + 8192  + ldst);
            gload16(gB1 + koff, Sd + 24576 + ldst);
        }
        bar();
        __builtin_amdgcn_s_setprio(1);
#pragma unroll
        for (int m = 0; m < 4; ++m)
#pragma unroll
            for (int n = 0; n < 2; ++n)
                acc[m][n] = __builtin_amdgcn_mfma_i32_32x32x32_i8(a1[m], b1[n], acc[m][n], 0, 0, 0);
        __builtin_amdgcn_s_setprio(0);

        // ---- end of K-tile: counted wait (never 0 mid-loop) ----
        if (t + 2 < NT) {
            asm volatile("s_waitcnt vmcnt(4)" ::: "memory");
        } else if (t + 1 < NT) {
            asm volatile("s_waitcnt vmcnt(0)" ::: "memory");
        }
        bar();

        cur = (cur == 2) ? 0 : cur + 1;
        nxt = (nxt == 2) ? 0 : nxt + 1;
    }

    // ---- epilogue: dequant + bias ----
    // C/D 32x32 layout: col = lane&31, row = (reg&3) + 8*(reg>>2) + 4*(lane>>5)
#pragma unroll
    for (int m = 0; m < 4; ++m) {
        const int rbase = bm0 + wr * 128 + m * 32 + 4 * hi;
        float xsv[16];
#pragma unroll
        for (int r = 0; r < 16; ++r)
            xsv[r] = xscale[rbase + (r & 3) + 8 * (r >> 2)];
#pragma unroll
        for (int n = 0; n < 2; ++n) {
            const int col = bn0 + wc * 64 + n * 32 + l31;
            const float wsc = wscale[col];
            const float bv  = bias[col];
#pragma unroll
            for (int r = 0; r < 16; ++r) {
                const int row = rbase + (r & 3) + 8 * (r >> 2);
                out[(size_t)row * OUT_F + col] = (float)acc[m][n][r] * xsv[r] * wsc + bv;
            }
        }
    }
}

extern "C" void kernel_launch(void* const* d_in, const int* in_sizes, int n_in,
                              void* d_out, int out_size, void* d_ws, size_t ws_size,
                              hipStream_t stream) {
    const float* x      = (const float*)d_in[0];
    const int*   w      = (const int*)d_in[1];     // int8 weights held as int32
    const float* wscale = (const float*)d_in[2];
    const float* bias   = (const float*)d_in[3];
    float* out = (float*)d_out;

    char* ws = (char*)d_ws;
    signed char* xq  = (signed char*)ws;                                   // 33.5 MB
    signed char* wq8 = (signed char*)(ws + (size_t)TOKENS * IN_F);         // 16.8 MB
    float* xscale    = (float*)(ws + (size_t)TOKENS * IN_F + (size_t)OUT_F * IN_F);

    hipFuncSetAttribute((const void*)gemm_kernel,
                        hipFuncAttributeMaxDynamicSharedMemorySize, LDS_TOTAL);

    quant_x_kernel<<<TOKENS, 256, 0, stream>>>(x, xq, xscale);
    pack_w_kernel<<<(OUT_F * (IN_F / 16)) / 256, 256, 0, stream>>>(w, wq8);
    gemm_kernel<<<(TOKENS / 256) * (OUT_F / 256), 512, LDS_TOTAL, stream>>>(
        xq, wq8, xscale, wscale, bias, out);
}

// Round 3
// 205.424 us; speedup vs baseline: 1.1440x; 1.0285x over previous
//
#include <hip/hip_runtime.h>
#include <cstdint>
#include <cstddef>

#define TOKENS 8192
#define IN_F   4096
#define OUT_F  4096
#define QMAXF  127.0f
#define EPSF   1e-8f

typedef int i32x4  __attribute__((ext_vector_type(4)));
typedef int i32x16 __attribute__((ext_vector_type(16)));

#define BKB 64                    // K-bytes (= int8 elems) per K-tile
#define NT  (IN_F / BKB)          // 64 K-tiles
#define LDS_BUF   32768           // A 16KB + B 16KB per buffer
#define LDS_TOTAL (3 * LDS_BUF)   // 98304 bytes

__device__ __forceinline__ void gload16(const void* g, void* l) {
    __builtin_amdgcn_global_load_lds(
        (const __attribute__((address_space(1))) void*)g,
        (__attribute__((address_space(3))) void*)l,
        16, 0, 0);
}

__device__ __forceinline__ void bar() {
    asm volatile("" ::: "memory");
    __builtin_amdgcn_s_barrier();
    asm volatile("" ::: "memory");
}

__device__ __forceinline__ int quant1(float v, float inv) {
    int q = (int)rintf(v * inv);
    q = q > 127 ? 127 : q;
    q = q < -127 ? -127 : q;
    return q;
}

__device__ __forceinline__ unsigned int pack4i(int a, int b, int c, int d) {
    return (unsigned int)(a & 255) | ((unsigned int)(b & 255) << 8) |
           ((unsigned int)(c & 255) << 16) | ((unsigned int)(d & 255) << 24);
}

// One block per token: absmax reduce + int8 quantize.
__global__ __launch_bounds__(256) void quant_x_kernel(const float* __restrict__ x,
                                                      signed char* __restrict__ xq,
                                                      float* __restrict__ xscale) {
    const int t   = blockIdx.x;
    const int tid = threadIdx.x;
    const float* xr = x + (size_t)t * IN_F + tid * 16;

    float4 v[4];
    float am = 0.0f;
#pragma unroll
    for (int i = 0; i < 4; ++i) {
        v[i] = ((const float4*)xr)[i];
        am = fmaxf(am, fmaxf(fmaxf(fabsf(v[i].x), fabsf(v[i].y)),
                             fmaxf(fabsf(v[i].z), fabsf(v[i].w))));
    }
#pragma unroll
    for (int off = 32; off >= 1; off >>= 1)
        am = fmaxf(am, __shfl_xor(am, off));

    __shared__ float wmax[4];
    const int wid = tid >> 6, lane = tid & 63;
    if (lane == 0) wmax[wid] = am;
    __syncthreads();
    am = fmaxf(fmaxf(wmax[0], wmax[1]), fmaxf(wmax[2], wmax[3]));

    const float s   = fmaxf(am, EPSF) / QMAXF;
    const float inv = QMAXF / fmaxf(am, EPSF);
    if (tid == 0) xscale[t] = s;

    unsigned int w[4];
#pragma unroll
    for (int i = 0; i < 4; ++i) {
        w[i] = pack4i(quant1(v[i].x, inv), quant1(v[i].y, inv),
                      quant1(v[i].z, inv), quant1(v[i].w, inv));
    }
    *(uint4*)(xq + (size_t)t * IN_F + tid * 16) = make_uint4(w[0], w[1], w[2], w[3]);
}

// Repack int32-held int8 weights into dense int8.
__global__ __launch_bounds__(256) void pack_w_kernel(const int* __restrict__ w,
                                                     signed char* __restrict__ wq) {
    const size_t idx = (size_t)blockIdx.x * 256 + threadIdx.x;
    const int4* src = (const int4*)w + idx * 4;
    unsigned int o[4];
#pragma unroll
    for (int i = 0; i < 4; ++i) {
        int4 u = src[i];
        o[i] = pack4i(u.x, u.y, u.z, u.w);
    }
    ((uint4*)wq)[idx] = make_uint4(o[0], o[1], o[2], o[3]);
}

// 256x256 tile, BK=64B, 8 waves (2x4), mfma_i32_32x32x32_i8,
// 3-buffer LDS, stage-2-ahead, counted vmcnt(4), 2 phases/K-tile.
// LDS layout (per 128-row group): window w=row>>4 (1024B, one wave's
// gload_lds target), within window: slot = granule*16 + (row&15)  [transposed]
// -> every ds_read_b128 fragment read is 4x 256B-contiguous chunks,
//    each covering all 32 banks exactly 2x (conflict-free).
__global__ __launch_bounds__(512, 2) void gemm_kernel(const signed char* __restrict__ xq,
                                                      const signed char* __restrict__ wq,
                                                      const float* __restrict__ xscale,
                                                      const float* __restrict__ wscale,
                                                      const float* __restrict__ bias,
                                                      float* __restrict__ out) {
    extern __shared__ __align__(16) char lds[];

    const int tid  = threadIdx.x;
    const int wid  = tid >> 6;
    const int lane = tid & 63;
    const int wr   = wid >> 2;   // 0..1
    const int wc   = wid & 3;    // 0..3
    const int bid  = blockIdx.x;
    const int bm0  = (bid & 31) * 256;
    const int bn0  = (bid >> 5) * 256;

    // ---- staging: lane slot l=tid&63 fetches (row = win*16 + (l&15), granule = l>>4) ----
    const int srow = (tid >> 6) * 16 + (tid & 15);   // row within 128-row group
    const int scol = ((tid >> 4) & 3) * 16;          // granule byte within 64B K-window
    const signed char* gA0 = xq + (size_t)(bm0 + srow)       * IN_F + scol;
    const signed char* gA1 = xq + (size_t)(bm0 + 128 + srow) * IN_F + scol;
    const signed char* gB0 = wq + (size_t)(bn0 + srow)       * IN_F + scol;
    const signed char* gB1 = wq + (size_t)(bn0 + 128 + srow) * IN_F + scol;
    const int ldst = tid * 16;

    // ---- fragment read offsets: P(R,g) = (R>>4)*1024 + g*256 + (R&15)*16 ----
    const int l31 = lane & 31, hi = lane >> 5;
    int a_off[4][2], b_off[2][2];
#pragma unroll
    for (int m = 0; m < 4; ++m) {
        const int rw = wr * 8 + m * 2 + (l31 >> 4);
        const int rb = (l31 & 15) * 16;
#pragma unroll
        for (int ks = 0; ks < 2; ++ks)
            a_off[m][ks] = rw * 1024 + (ks * 2 + hi) * 256 + rb;
    }
#pragma unroll
    for (int n = 0; n < 2; ++n) {
        const int rw = wc * 4 + n * 2 + (l31 >> 4);
        const int rb = (l31 & 15) * 16;
#pragma unroll
        for (int ks = 0; ks < 2; ++ks)
            b_off[n][ks] = 16384 + rw * 1024 + (ks * 2 + hi) * 256 + rb;
    }

    i32x16 acc[4][2];
#pragma unroll
    for (int m = 0; m < 4; ++m)
#pragma unroll
        for (int n = 0; n < 2; ++n)
#pragma unroll
            for (int r = 0; r < 16; ++r) acc[m][n][r] = 0;

    // ---- prologue: stage tile0 -> buf0, tile1 -> buf1 ----
    {
        char* S0 = lds;
        gload16(gA0,       S0 + ldst);
        gload16(gA1,       S0 + 8192  + ldst);
        gload16(gB0,       S0 + 16384 + ldst);
        gload16(gB1,       S0 + 24576 + ldst);
        char* S1 = lds + LDS_BUF;
        gload16(gA0 + BKB, S1 + ldst);
        gload16(gA1 + BKB, S1 + 8192  + ldst);
        gload16(gB0 + BKB, S1 + 16384 + ldst);
        gload16(gB1 + BKB, S1 + 24576 + ldst);
    }
    asm volatile("s_waitcnt vmcnt(4)" ::: "memory");
    bar();

    int cur = 0, nxt = 2;
    for (int t = 0; t < NT; ++t) {
        const char* Ab = lds + cur * LDS_BUF;
        char* Sd = lds + nxt * LDS_BUF;
        const bool st = (t + 2 < NT);
        const int koff = (t + 2) * BKB;

        // ---------- phase 0 (ks = 0) ----------
        i32x4 a0[4], b0[2];
#pragma unroll
        for (int m = 0; m < 4; ++m) a0[m] = *(const i32x4*)(Ab + a_off[m][0]);
#pragma unroll
        for (int n = 0; n < 2; ++n) b0[n] = *(const i32x4*)(Ab + b_off[n][0]);
        if (st) {
            gload16(gA0 + koff, Sd + ldst);
            gload16(gB0 + koff, Sd + 16384 + ldst);
        }
        bar();
        __builtin_amdgcn_s_setprio(1);
#pragma unroll
        for (int m = 0; m < 4; ++m)
#pragma unroll
            for (int n = 0; n < 2; ++n)
                acc[m][n] = __builtin_amdgcn_mfma_i32_32x32x32_i8(a0[m], b0[n], acc[m][n], 0, 0, 0);
        __builtin_amdgcn_s_setprio(0);
        bar();

        // ---------- phase 1 (ks = 1) ----------
        i32x4 a1[4], b1[2];
#pragma unroll
        for (int m = 0; m < 4; ++m) a1[m] = *(const i32x4*)(Ab + a_off[m][1]);
#pragma unroll
        for (int n = 0; n < 2; ++n) b1[n] = *(const i32x4*)(Ab + b_off[n][1]);
        if (st) {
            gload16(gA1 + koff, Sd + 8192  + ldst);
            gload16(gB1 + koff, Sd + 24576 + ldst);
        }
        bar();
        __builtin_amdgcn_s_setprio(1);
#pragma unroll
        for (int m = 0; m < 4; ++m)
#pragma unroll
            for (int n = 0; n < 2; ++n)
                acc[m][n] = __builtin_amdgcn_mfma_i32_32x32x32_i8(a1[m], b1[n], acc[m][n], 0, 0, 0);
        __builtin_amdgcn_s_setprio(0);

        // ---- end of K-tile: counted wait (never 0 mid-loop) ----
        if (t + 2 < NT) {
            asm volatile("s_waitcnt vmcnt(4)" ::: "memory");
        } else if (t + 1 < NT) {
            asm volatile("s_waitcnt vmcnt(0)" ::: "memory");
        }
        bar();

        cur = (cur == 2) ? 0 : cur + 1;
        nxt = (nxt == 2) ? 0 : nxt + 1;
    }

    // ---- epilogue: dequant + bias ----
    // C/D 32x32 layout: col = lane&31, row = (reg&3) + 8*(reg>>2) + 4*(lane>>5)
#pragma unroll
    for (int m = 0; m < 4; ++m) {
        const int rbase = bm0 + wr * 128 + m * 32 + 4 * hi;
        float xsv[16];
#pragma unroll
        for (int r = 0; r < 16; ++r)
            xsv[r] = xscale[rbase + (r & 3) + 8 * (r >> 2)];
#pragma unroll
        for (int n = 0; n < 2; ++n) {
            const int col = bn0 + wc * 64 + n * 32 + l31;
            const float wsc = wscale[col];
            const float bv  = bias[col];
#pragma unroll
            for (int r = 0; r < 16; ++r) {
                const int row = rbase + (r & 3) + 8 * (r >> 2);
                out[(size_t)row * OUT_F + col] = (float)acc[m][n][r] * xsv[r] * wsc + bv;
            }
        }
    }
}

extern "C" void kernel_launch(void* const* d_in, const int* in_sizes, int n_in,
                              void* d_out, int out_size, void* d_ws, size_t ws_size,
                              hipStream_t stream) {
    const float* x      = (const float*)d_in[0];
    const int*   w      = (const int*)d_in[1];     // int8 weights held as int32
    const float* wscale = (const float*)d_in[2];
    const float* bias   = (const float*)d_in[3];
    float* out = (float*)d_out;

    char* ws = (char*)d_ws;
    signed char* xq  = (signed char*)ws;                                   // 33.5 MB
    signed char* wq8 = (signed char*)(ws + (size_t)TOKENS * IN_F);         // 16.8 MB
    float* xscale    = (float*)(ws + (size_t)TOKENS * IN_F + (size_t)OUT_F * IN_F);

    hipFuncSetAttribute((const void*)gemm_kernel,
                        hipFuncAttributeMaxDynamicSharedMemorySize, LDS_TOTAL);

    quant_x_kernel<<<TOKENS, 256, 0, stream>>>(x, xq, xscale);
    pack_w_kernel<<<(OUT_F * (IN_F / 16)) / 256, 256, 0, stream>>>(w, wq8);
    gemm_kernel<<<(TOKENS / 256) * (OUT_F / 256), 512, LDS_TOTAL, stream>>>(
        xq, wq8, xscale, wscale, bias, out);
}